// Round 1
// baseline (884.351 us; speedup 1.0000x reference)
//
#include <hip/hip_runtime.h>
#include <math.h>

#define N_NODES 50000
#define N_EDGES 800000

using short8  = __attribute__((ext_vector_type(8))) short;
using floatx4 = __attribute__((ext_vector_type(4))) float;
using floatx2 = __attribute__((ext_vector_type(2))) float;
using ushortx4 = __attribute__((ext_vector_type(4))) unsigned short;

__device__ inline unsigned short f2bf(float f) {
  unsigned u = __float_as_uint(f);
  u += 0x7fff + ((u >> 16) & 1);   // round-to-nearest-even
  return (unsigned short)(u >> 16);
}

__device__ inline float sigmoidf(float x) { return 1.0f / (1.0f + __expf(-x)); }

// ---------------- CSR build ----------------

__global__ void count_kernel(const int* __restrict__ rows, int* __restrict__ counts, int E) {
  int e = blockIdx.x * 256 + threadIdx.x;
  if (e < E) atomicAdd(&counts[rows[e]], 1);
}

__global__ void scan_kernel(const int* __restrict__ counts, int* __restrict__ row_ptr,
                            int* __restrict__ cursor, int N) {
  __shared__ int wave_sums[4];
  __shared__ int carry_s;
  int tid = threadIdx.x, lane = tid & 63, wid = tid >> 6;
  if (tid == 0) carry_s = 0;
  __syncthreads();
  for (int base = 0; base < N; base += 256) {
    int i = base + tid;
    int v = (i < N) ? counts[i] : 0;
    int x = v;
#pragma unroll
    for (int d = 1; d < 64; d <<= 1) {
      int y = __shfl_up(x, d, 64);
      if (lane >= d) x += y;
    }
    if (lane == 63) wave_sums[wid] = x;
    __syncthreads();
    int woff = 0;
    for (int w = 0; w < wid; ++w) woff += wave_sums[w];
    int incl = x + woff;          // inclusive block scan
    int excl = incl - v;
    int carry = carry_s;
    if (i < N) { row_ptr[i] = carry + excl; cursor[i] = carry + excl; }
    __syncthreads();
    if (tid == 255) carry_s = carry + incl;   // incl of last thread = chunk total
    __syncthreads();
  }
  if (threadIdx.x == 0) row_ptr[N] = carry_s;
}

__global__ void scatter_kernel(const int* __restrict__ rows, const int* __restrict__ cols,
                               const float* __restrict__ vals, int* __restrict__ cursor,
                               int* __restrict__ col_idx, float* __restrict__ val_srt, int E) {
  int e = blockIdx.x * 256 + threadIdx.x;
  if (e >= E) return;
  int r = rows[e];
  int p = atomicAdd(&cursor[r], 1);
  col_idx[p] = cols[e];
  val_srt[p] = vals[e];
}

// ---------------- casts / packing ----------------

__global__ void cast_bf16x4_kernel(const float* __restrict__ x, unsigned short* __restrict__ xb, int n4) {
  int i = blockIdx.x * 256 + threadIdx.x;
  if (i >= n4) return;
  floatx4 v = ((const floatx4*)x)[i];
  ushortx4 o;
  o[0] = f2bf(v[0]); o[1] = f2bf(v[1]); o[2] = f2bf(v[2]); o[3] = f2bf(v[3]);
  ((ushortx4*)xb)[i] = o;
}

// W is [K,M] row-major (in_dim, out_dim); Wp[m*K + k] = bf16(W[k,m])  (B^T layout, k contiguous)
__global__ void pack_w_kernel(const float* __restrict__ W, unsigned short* __restrict__ Wp, int K, int M) {
  int idx = blockIdx.x * 256 + threadIdx.x;
  if (idx >= K * M) return;
  int m = idx / K, k = idx - m * K;
  Wp[idx] = f2bf(W[(size_t)k * M + m]);
}

// ---------------- GEMM: C[N,M] = A[N,K=256] (bf16) @ B (Bp packed [M,K] bf16), f32 out ----------------
// wave computes a 16-row x M strip; MT = M/16 tiles of 16 cols.
// A frag: lane holds A[m=lane&15][k=quad*8+j]; B frag: B[k=quad*8+j][n=lane&15];
// C/D: lane holds D[row=quad*4+reg][col=lane&15]  (verified mappings, learn_hip m89/m91)
template <int MT>
__global__ __launch_bounds__(256) void gemm_bf16_kernel(const unsigned short* __restrict__ A,
                                                        const unsigned short* __restrict__ Bp,
                                                        float* __restrict__ C, int N) {
  constexpr int K = 256;
  constexpr int M = MT * 16;
  int lane = threadIdx.x & 63;
  int wid = threadIdx.x >> 6;
  int tile = blockIdx.x * 4 + wid;
  int r0 = tile * 16;
  if (r0 >= N) return;
  int quad = lane >> 4, lr = lane & 15;
  const short* Abase = (const short*)A + (size_t)(r0 + lr) * K + quad * 8;
  const short* Bbase = (const short*)Bp + (size_t)lr * K + quad * 8;
  floatx4 zero = {0.f, 0.f, 0.f, 0.f};
  floatx4 acc[MT];
#pragma unroll
  for (int t = 0; t < MT; ++t) acc[t] = zero;
  for (int kc = 0; kc < K / 32; ++kc) {
    short8 a = *(const short8*)(Abase + kc * 32);
#pragma unroll
    for (int t = 0; t < MT; ++t) {
      short8 b = *(const short8*)(Bbase + (size_t)t * 16 * K + kc * 32);
      acc[t] = __builtin_amdgcn_mfma_f32_16x16x32_bf16(a, b, acc[t], 0, 0, 0);
    }
  }
  int orow = r0 + quad * 4;
#pragma unroll
  for (int t = 0; t < MT; ++t)
#pragma unroll
    for (int g = 0; g < 4; ++g)
      C[(size_t)(orow + g) * M + t * 16 + lr] = acc[t][g];
}

// ---------------- fused SpMM pair + gating ----------------
// One wave per output row r: acc_s = sum val*S[col], acc_g = sum val*G[col].
// WRITE_H: hb[r] = bf16(relu(sigmoid(acc_g)*acc_s));  else: out[r] = sigmoid(acc_g)*acc_s (f32)
template <int D, bool WRITE_H>
__global__ __launch_bounds__(256) void spmm_gated_kernel(const int* __restrict__ row_ptr,
                                                         const int* __restrict__ col_idx,
                                                         const float* __restrict__ val,
                                                         const float* __restrict__ S,
                                                         const float* __restrict__ G,
                                                         unsigned short* __restrict__ hb,
                                                         float* __restrict__ out, int N) {
  int lane = threadIdx.x & 63;
  int wid = threadIdx.x >> 6;
  int r = blockIdx.x * 4 + wid;
  if (r >= N) return;
  int e0 = row_ptr[r], e1 = row_ptr[r + 1];
  if constexpr (D == 256) {
    floatx4 aS = {0.f, 0.f, 0.f, 0.f}, aG = {0.f, 0.f, 0.f, 0.f};
    for (int e = e0; e < e1; ++e) {
      int c = col_idx[e];
      float v = val[e];
      floatx4 s = ((const floatx4*)(S + (size_t)c * D))[lane];
      floatx4 g = ((const floatx4*)(G + (size_t)c * D))[lane];
      aS += s * v;
      aG += g * v;
    }
    if constexpr (WRITE_H) {
      ushortx4 o;
#pragma unroll
      for (int i = 0; i < 4; ++i) {
        float h = sigmoidf(aG[i]) * aS[i];
        o[i] = f2bf(h > 0.f ? h : 0.f);
      }
      ((ushortx4*)(hb + (size_t)r * D))[lane] = o;
    } else {
      floatx4 o;
#pragma unroll
      for (int i = 0; i < 4; ++i) o[i] = sigmoidf(aG[i]) * aS[i];
      ((floatx4*)(out + (size_t)r * D))[lane] = o;
    }
  } else {  // D == 128
    floatx2 aS = {0.f, 0.f}, aG = {0.f, 0.f};
    for (int e = e0; e < e1; ++e) {
      int c = col_idx[e];
      float v = val[e];
      floatx2 s = ((const floatx2*)(S + (size_t)c * D))[lane];
      floatx2 g = ((const floatx2*)(G + (size_t)c * D))[lane];
      aS += s * v;
      aG += g * v;
    }
    if constexpr (WRITE_H) {
      unsigned short o[2];
#pragma unroll
      for (int i = 0; i < 2; ++i) {
        float h = sigmoidf(aG[i]) * aS[i];
        o[i] = f2bf(h > 0.f ? h : 0.f);
      }
      hb[(size_t)r * D + lane * 2] = o[0];
      hb[(size_t)r * D + lane * 2 + 1] = o[1];
    } else {
      floatx2 o;
#pragma unroll
      for (int i = 0; i < 2; ++i) o[i] = sigmoidf(aG[i]) * aS[i];
      ((floatx2*)(out + (size_t)r * D))[lane] = o;
    }
  }
}

// ---------------- launch ----------------

extern "C" void kernel_launch(void* const* d_in, const int* in_sizes, int n_in,
                              void* d_out, int out_size, void* d_ws, size_t ws_size,
                              hipStream_t stream) {
  const float* x    = (const float*)d_in[0];
  const int*   rows = (const int*)d_in[1];
  const int*   cols = (const int*)d_in[2];
  const float* vals = (const float*)d_in[3];
  const float* W1   = (const float*)d_in[4];
  const float* G1   = (const float*)d_in[5];
  const float* W2   = (const float*)d_in[6];
  const float* G2   = (const float*)d_in[7];

  const int N = N_NODES, E = N_EDGES;
  char* ws = (char*)d_ws;
  size_t off = 0;
  auto alloc = [&](size_t bytes) -> char* {
    off = (off + 255) & ~(size_t)255;
    char* p = ws + off;
    off += bytes;
    return p;
  };
  int*   counts  = (int*)alloc((size_t)N * 4);
  int*   row_ptr = (int*)alloc((size_t)(N + 1) * 4);
  int*   cursor  = (int*)alloc((size_t)N * 4);
  int*   col_idx = (int*)alloc((size_t)E * 4);
  float* val_srt = (float*)alloc((size_t)E * 4);
  unsigned short* xb  = (unsigned short*)alloc((size_t)N * 256 * 2);
  unsigned short* hb  = (unsigned short*)alloc((size_t)N * 256 * 2);
  unsigned short* Wp1 = (unsigned short*)alloc(256 * 256 * 2);
  unsigned short* Gp1 = (unsigned short*)alloc(256 * 256 * 2);
  unsigned short* Wp2 = (unsigned short*)alloc(256 * 128 * 2);
  unsigned short* Gp2 = (unsigned short*)alloc(256 * 128 * 2);
  float* bufS = (float*)alloc((size_t)N * 256 * 4);
  float* bufG = (float*)alloc((size_t)N * 256 * 4);

  // CSR build (per launch; same work every call)
  hipMemsetAsync(counts, 0, (size_t)N * 4, stream);
  count_kernel<<<(E + 255) / 256, 256, 0, stream>>>(rows, counts, E);
  scan_kernel<<<1, 256, 0, stream>>>(counts, row_ptr, cursor, N);
  scatter_kernel<<<(E + 255) / 256, 256, 0, stream>>>(rows, cols, vals, cursor, col_idx, val_srt, E);

  // casts
  int n4 = N * 256 / 4;
  cast_bf16x4_kernel<<<(n4 + 255) / 256, 256, 0, stream>>>(x, xb, n4);
  pack_w_kernel<<<(256 * 256 + 255) / 256, 256, 0, stream>>>(W1, Wp1, 256, 256);
  pack_w_kernel<<<(256 * 256 + 255) / 256, 256, 0, stream>>>(G1, Gp1, 256, 256);
  pack_w_kernel<<<(256 * 128 + 255) / 256, 256, 0, stream>>>(W2, Wp2, 256, 128);
  pack_w_kernel<<<(256 * 128 + 255) / 256, 256, 0, stream>>>(G2, Gp2, 256, 128);

  int gemm_blocks = ((N + 15) / 16 + 3) / 4;
  int spmm_blocks = (N + 3) / 4;

  // layer 1
  gemm_bf16_kernel<16><<<gemm_blocks, 256, 0, stream>>>(xb, Wp1, bufS, N);
  gemm_bf16_kernel<16><<<gemm_blocks, 256, 0, stream>>>(xb, Gp1, bufG, N);
  spmm_gated_kernel<256, true><<<spmm_blocks, 256, 0, stream>>>(row_ptr, col_idx, val_srt,
                                                                bufS, bufG, hb, nullptr, N);
  // layer 2
  gemm_bf16_kernel<8><<<gemm_blocks, 256, 0, stream>>>(hb, Wp2, bufS, N);
  gemm_bf16_kernel<8><<<gemm_blocks, 256, 0, stream>>>(hb, Gp2, bufG, N);
  spmm_gated_kernel<128, false><<<spmm_blocks, 256, 0, stream>>>(row_ptr, col_idx, val_srt,
                                                                 bufS, bufG, nullptr, (float*)d_out, N);
}

// Round 3
// 701.947 us; speedup vs baseline: 1.2599x; 1.2599x over previous
//
#include <hip/hip_runtime.h>
#include <math.h>

#define N_NODES 50000
#define N_EDGES 800000

using short8  = __attribute__((ext_vector_type(8))) short;
using shortx4 = __attribute__((ext_vector_type(4))) short;
using floatx4 = __attribute__((ext_vector_type(4))) float;
using floatx2 = __attribute__((ext_vector_type(2))) float;
using ushortx4 = __attribute__((ext_vector_type(4))) unsigned short;

__device__ inline unsigned short f2bf(float f) {
  unsigned u = __float_as_uint(f);
  u += 0x7fff + ((u >> 16) & 1);   // round-to-nearest-even
  return (unsigned short)(u >> 16);
}

__device__ inline float bf2f(short s) {
  return __uint_as_float(((unsigned)(unsigned short)s) << 16);
}

__device__ inline float sigmoidf(float x) { return 1.0f / (1.0f + __expf(-x)); }

// ---------------- CSR build ----------------

__global__ void count_kernel(const int* __restrict__ rows, int* __restrict__ counts, int E) {
  int e = blockIdx.x * 256 + threadIdx.x;
  if (e < E) atomicAdd(&counts[rows[e]], 1);
}

__global__ void scan_kernel(const int* __restrict__ counts, int* __restrict__ row_ptr,
                            int* __restrict__ cursor, int N) {
  __shared__ int wave_sums[4];
  __shared__ int carry_s;
  int tid = threadIdx.x, lane = tid & 63, wid = tid >> 6;
  if (tid == 0) carry_s = 0;
  __syncthreads();
  for (int base = 0; base < N; base += 256) {
    int i = base + tid;
    int v = (i < N) ? counts[i] : 0;
    int x = v;
#pragma unroll
    for (int d = 1; d < 64; d <<= 1) {
      int y = __shfl_up(x, d, 64);
      if (lane >= d) x += y;
    }
    if (lane == 63) wave_sums[wid] = x;
    __syncthreads();
    int woff = 0;
    for (int w = 0; w < wid; ++w) woff += wave_sums[w];
    int incl = x + woff;          // inclusive block scan
    int excl = incl - v;
    int carry = carry_s;
    if (i < N) { row_ptr[i] = carry + excl; cursor[i] = carry + excl; }
    __syncthreads();
    if (tid == 255) carry_s = carry + incl;   // incl of last thread = chunk total
    __syncthreads();
  }
  if (threadIdx.x == 0) row_ptr[N] = carry_s;
}

__global__ void scatter_kernel(const int* __restrict__ rows, const int* __restrict__ cols,
                               const float* __restrict__ vals, int* __restrict__ cursor,
                               int* __restrict__ col_idx, float* __restrict__ val_srt, int E) {
  int e = blockIdx.x * 256 + threadIdx.x;
  if (e >= E) return;
  int r = rows[e];
  int p = atomicAdd(&cursor[r], 1);
  col_idx[p] = cols[e];
  val_srt[p] = vals[e];
}

// ---------------- casts / packing ----------------

__global__ void cast_bf16x4_kernel(const float* __restrict__ x, unsigned short* __restrict__ xb, int n4) {
  int i = blockIdx.x * 256 + threadIdx.x;
  if (i >= n4) return;
  floatx4 v = ((const floatx4*)x)[i];
  ushortx4 o;
  o[0] = f2bf(v[0]); o[1] = f2bf(v[1]); o[2] = f2bf(v[2]); o[3] = f2bf(v[3]);
  ((ushortx4*)xb)[i] = o;
}

// W is [K,M] row-major (in_dim, out_dim); Wp[m*K + k] = bf16(W[k,m])  (B^T layout, k contiguous)
__global__ void pack_w_kernel(const float* __restrict__ W, unsigned short* __restrict__ Wp, int K, int M) {
  int idx = blockIdx.x * 256 + threadIdx.x;
  if (idx >= K * M) return;
  int m = idx / K, k = idx - m * K;
  Wp[idx] = f2bf(W[(size_t)k * M + m]);
}

// ---------------- fused dual GEMM: S = A@W, G = A@G, written interleaved bf16 ----------------
// A [N,256] bf16; Wp/Gp packed [M,K] bf16; SG out: row r has 2M shorts, SG[r][2m]=S, SG[r][2m+1]=G.
// wave = 16 rows x M cols. A frag: lane holds A[m=lane&15][k=quad*8+j];
// C/D: lane holds D[row=quad*4+reg][col=lane&15]  (verified, learn_hip m89/m91)
template <int MT>
__global__ __launch_bounds__(256) void gemm_dual_kernel(const unsigned short* __restrict__ A,
                                                        const unsigned short* __restrict__ Wp,
                                                        const unsigned short* __restrict__ Gp,
                                                        unsigned* __restrict__ SG, int N) {
  constexpr int K = 256;
  constexpr int M = MT * 16;
  int lane = threadIdx.x & 63;
  int wid = threadIdx.x >> 6;
  int tile = blockIdx.x * 4 + wid;
  int r0 = tile * 16;
  if (r0 >= N) return;
  int quad = lane >> 4, lr = lane & 15;
  const short* Abase = (const short*)A + (size_t)(r0 + lr) * K + quad * 8;
  const short* Wbase = (const short*)Wp + (size_t)lr * K + quad * 8;
  const short* Gbase = (const short*)Gp + (size_t)lr * K + quad * 8;
  floatx4 zero = {0.f, 0.f, 0.f, 0.f};
  floatx4 accS[MT], accG[MT];
#pragma unroll
  for (int t = 0; t < MT; ++t) { accS[t] = zero; accG[t] = zero; }
  for (int kc = 0; kc < K / 32; ++kc) {
    short8 a = *(const short8*)(Abase + kc * 32);
#pragma unroll
    for (int t = 0; t < MT; ++t) {
      short8 bw = *(const short8*)(Wbase + (size_t)t * 16 * K + kc * 32);
      short8 bg = *(const short8*)(Gbase + (size_t)t * 16 * K + kc * 32);
      accS[t] = __builtin_amdgcn_mfma_f32_16x16x32_bf16(a, bw, accS[t], 0, 0, 0);
      accG[t] = __builtin_amdgcn_mfma_f32_16x16x32_bf16(a, bg, accG[t], 0, 0, 0);
    }
  }
  int orow = r0 + quad * 4;
#pragma unroll
  for (int t = 0; t < MT; ++t)
#pragma unroll
    for (int g = 0; g < 4; ++g) {
      unsigned s = f2bf(accS[t][g]);
      unsigned gg = f2bf(accG[t][g]);
      SG[(size_t)(orow + g) * M + t * 16 + lr] = s | (gg << 16);
    }
}

// ---------------- fused SpMM pair + gating (bf16 interleaved SG input) ----------------
// One wave per output row r. Per edge: single 16B (D=256) / 8B (D=128) gather per lane,
// covering interleaved {S,G} pairs. Unroll x4 for memory-level parallelism.
template <int D, bool WRITE_H>
__global__ __launch_bounds__(256) void spmm_gated_kernel(const int* __restrict__ row_ptr,
                                                         const int* __restrict__ col_idx,
                                                         const float* __restrict__ val,
                                                         const unsigned short* __restrict__ SG,
                                                         unsigned short* __restrict__ hb,
                                                         float* __restrict__ out, int N) {
  int lane = threadIdx.x & 63;
  int wid = threadIdx.x >> 6;
  int r = blockIdx.x * 4 + wid;
  if (r >= N) return;
  int e0 = row_ptr[r], e1 = row_ptr[r + 1];

  if constexpr (D == 256) {
    float aS[4] = {0.f, 0.f, 0.f, 0.f}, aG[4] = {0.f, 0.f, 0.f, 0.f};
    int e = e0;
    for (; e + 4 <= e1; e += 4) {
      int c0 = col_idx[e], c1 = col_idx[e + 1], c2 = col_idx[e + 2], c3 = col_idx[e + 3];
      float v0 = val[e], v1 = val[e + 1], v2 = val[e + 2], v3 = val[e + 3];
      short8 p0 = ((const short8*)(SG + (size_t)c0 * 512))[lane];
      short8 p1 = ((const short8*)(SG + (size_t)c1 * 512))[lane];
      short8 p2 = ((const short8*)(SG + (size_t)c2 * 512))[lane];
      short8 p3 = ((const short8*)(SG + (size_t)c3 * 512))[lane];
#pragma unroll
      for (int i = 0; i < 4; ++i) { aS[i] += bf2f(p0[2*i]) * v0; aG[i] += bf2f(p0[2*i+1]) * v0; }
#pragma unroll
      for (int i = 0; i < 4; ++i) { aS[i] += bf2f(p1[2*i]) * v1; aG[i] += bf2f(p1[2*i+1]) * v1; }
#pragma unroll
      for (int i = 0; i < 4; ++i) { aS[i] += bf2f(p2[2*i]) * v2; aG[i] += bf2f(p2[2*i+1]) * v2; }
#pragma unroll
      for (int i = 0; i < 4; ++i) { aS[i] += bf2f(p3[2*i]) * v3; aG[i] += bf2f(p3[2*i+1]) * v3; }
    }
    for (; e < e1; ++e) {
      int c = col_idx[e];
      float v = val[e];
      short8 p = ((const short8*)(SG + (size_t)c * 512))[lane];
#pragma unroll
      for (int i = 0; i < 4; ++i) { aS[i] += bf2f(p[2*i]) * v; aG[i] += bf2f(p[2*i+1]) * v; }
    }
    if constexpr (WRITE_H) {
      ushortx4 o;
#pragma unroll
      for (int i = 0; i < 4; ++i) {
        float h = sigmoidf(aG[i]) * aS[i];
        o[i] = f2bf(h > 0.f ? h : 0.f);
      }
      ((ushortx4*)(hb + (size_t)r * 256))[lane] = o;
    } else {
      floatx4 o;
#pragma unroll
      for (int i = 0; i < 4; ++i) o[i] = sigmoidf(aG[i]) * aS[i];
      ((floatx4*)(out + (size_t)r * 256))[lane] = o;
    }
  } else {  // D == 128
    float aS[2] = {0.f, 0.f}, aG[2] = {0.f, 0.f};
    int e = e0;
    for (; e + 4 <= e1; e += 4) {
      int c0 = col_idx[e], c1 = col_idx[e + 1], c2 = col_idx[e + 2], c3 = col_idx[e + 3];
      float v0 = val[e], v1 = val[e + 1], v2 = val[e + 2], v3 = val[e + 3];
      shortx4 p0 = ((const shortx4*)(SG + (size_t)c0 * 256))[lane];
      shortx4 p1 = ((const shortx4*)(SG + (size_t)c1 * 256))[lane];
      shortx4 p2 = ((const shortx4*)(SG + (size_t)c2 * 256))[lane];
      shortx4 p3 = ((const shortx4*)(SG + (size_t)c3 * 256))[lane];
#pragma unroll
      for (int i = 0; i < 2; ++i) { aS[i] += bf2f(p0[2*i]) * v0; aG[i] += bf2f(p0[2*i+1]) * v0; }
#pragma unroll
      for (int i = 0; i < 2; ++i) { aS[i] += bf2f(p1[2*i]) * v1; aG[i] += bf2f(p1[2*i+1]) * v1; }
#pragma unroll
      for (int i = 0; i < 2; ++i) { aS[i] += bf2f(p2[2*i]) * v2; aG[i] += bf2f(p2[2*i+1]) * v2; }
#pragma unroll
      for (int i = 0; i < 2; ++i) { aS[i] += bf2f(p3[2*i]) * v3; aG[i] += bf2f(p3[2*i+1]) * v3; }
    }
    for (; e < e1; ++e) {
      int c = col_idx[e];
      float v = val[e];
      shortx4 p = ((const shortx4*)(SG + (size_t)c * 256))[lane];
#pragma unroll
      for (int i = 0; i < 2; ++i) { aS[i] += bf2f(p[2*i]) * v; aG[i] += bf2f(p[2*i+1]) * v; }
    }
    floatx2 o;
#pragma unroll
    for (int i = 0; i < 2; ++i) o[i] = sigmoidf(aG[i]) * aS[i];
    ((floatx2*)(out + (size_t)r * 128))[lane] = o;
  }
}

// ---------------- launch ----------------

extern "C" void kernel_launch(void* const* d_in, const int* in_sizes, int n_in,
                              void* d_out, int out_size, void* d_ws, size_t ws_size,
                              hipStream_t stream) {
  const float* x    = (const float*)d_in[0];
  const int*   rows = (const int*)d_in[1];
  const int*   cols = (const int*)d_in[2];
  const float* vals = (const float*)d_in[3];
  const float* W1   = (const float*)d_in[4];
  const float* G1   = (const float*)d_in[5];
  const float* W2   = (const float*)d_in[6];
  const float* G2   = (const float*)d_in[7];

  const int N = N_NODES, E = N_EDGES;
  char* ws = (char*)d_ws;
  size_t off = 0;
  auto alloc = [&](size_t bytes) -> char* {
    off = (off + 255) & ~(size_t)255;
    char* p = ws + off;
    off += bytes;
    return p;
  };
  int*   counts  = (int*)alloc((size_t)N * 4);
  int*   row_ptr = (int*)alloc((size_t)(N + 1) * 4);
  int*   cursor  = (int*)alloc((size_t)N * 4);
  int*   col_idx = (int*)alloc((size_t)E * 4);
  float* val_srt = (float*)alloc((size_t)E * 4);
  unsigned short* xb  = (unsigned short*)alloc((size_t)N * 256 * 2);
  unsigned short* hb  = (unsigned short*)alloc((size_t)N * 256 * 2);
  unsigned short* Wp1 = (unsigned short*)alloc(256 * 256 * 2);
  unsigned short* Gp1 = (unsigned short*)alloc(256 * 256 * 2);
  unsigned short* Wp2 = (unsigned short*)alloc(256 * 128 * 2);
  unsigned short* Gp2 = (unsigned short*)alloc(256 * 128 * 2);
  unsigned* SG1 = (unsigned*)alloc((size_t)N * 256 * 4);   // [N][256] uints = {S,G} bf16 pairs
  unsigned* SG2 = (unsigned*)alloc((size_t)N * 128 * 4);   // [N][128] uints

  // CSR build (per launch; same work every call)
  (void)hipMemsetAsync(counts, 0, (size_t)N * 4, stream);
  count_kernel<<<(E + 255) / 256, 256, 0, stream>>>(rows, counts, E);
  scan_kernel<<<1, 256, 0, stream>>>(counts, row_ptr, cursor, N);
  scatter_kernel<<<(E + 255) / 256, 256, 0, stream>>>(rows, cols, vals, cursor, col_idx, val_srt, E);

  // casts
  int n4 = N * 256 / 4;
  cast_bf16x4_kernel<<<(n4 + 255) / 256, 256, 0, stream>>>(x, xb, n4);
  pack_w_kernel<<<(256 * 256 + 255) / 256, 256, 0, stream>>>(W1, Wp1, 256, 256);
  pack_w_kernel<<<(256 * 256 + 255) / 256, 256, 0, stream>>>(G1, Gp1, 256, 256);
  pack_w_kernel<<<(256 * 128 + 255) / 256, 256, 0, stream>>>(W2, Wp2, 256, 128);
  pack_w_kernel<<<(256 * 128 + 255) / 256, 256, 0, stream>>>(G2, Gp2, 256, 128);

  int gemm_blocks = ((N + 15) / 16 + 3) / 4;
  int spmm_blocks = (N + 3) / 4;

  // layer 1
  gemm_dual_kernel<16><<<gemm_blocks, 256, 0, stream>>>(xb, Wp1, Gp1, SG1, N);
  spmm_gated_kernel<256, true><<<spmm_blocks, 256, 0, stream>>>(row_ptr, col_idx, val_srt,
                                                                (const unsigned short*)SG1, hb, nullptr, N);
  // layer 2
  gemm_dual_kernel<8><<<gemm_blocks, 256, 0, stream>>>(hb, Wp2, Gp2, SG2, N);
  spmm_gated_kernel<128, false><<<spmm_blocks, 256, 0, stream>>>(row_ptr, col_idx, val_srt,
                                                                 (const unsigned short*)SG2, nullptr, (float*)d_out, N);
}

// Round 4
// 463.538 us; speedup vs baseline: 1.9078x; 1.5143x over previous
//
#include <hip/hip_runtime.h>
#include <math.h>

#define N_NODES 50000
#define N_EDGES 800000
#define SCAN_BLK 2048   // elements per scan block (256 threads x 8)

using short8  = __attribute__((ext_vector_type(8))) short;
using shortx4 = __attribute__((ext_vector_type(4))) short;
using floatx4 = __attribute__((ext_vector_type(4))) float;
using floatx2 = __attribute__((ext_vector_type(2))) float;
using ushortx4 = __attribute__((ext_vector_type(4))) unsigned short;

__device__ inline unsigned short f2bf(float f) {
  unsigned u = __float_as_uint(f);
  u += 0x7fff + ((u >> 16) & 1);   // round-to-nearest-even
  return (unsigned short)(u >> 16);
}

__device__ inline float bf2f(short s) {
  return __uint_as_float(((unsigned)(unsigned short)s) << 16);
}

__device__ inline float sigmoidf(float x) { return 1.0f / (1.0f + __expf(-x)); }

// ---------------- CSR build ----------------

__global__ void count_kernel(const int* __restrict__ rows, int* __restrict__ counts, int E) {
  int e = blockIdx.x * 256 + threadIdx.x;
  if (e < E) atomicAdd(&counts[rows[e]], 1);
}

// pass1: per-block sums. N % 8 == 0 so (base < N) => full 8 in-bounds.
__global__ void scan_pass1(const int* __restrict__ counts, int* __restrict__ bsum, int N) {
  int base = blockIdx.x * SCAN_BLK + threadIdx.x * 8;
  int s = 0;
  if (base < N) {
#pragma unroll
    for (int j = 0; j < 8; ++j) s += counts[base + j];
  }
#pragma unroll
  for (int d = 32; d > 0; d >>= 1) s += __shfl_down(s, d, 64);
  __shared__ int wsum[4];
  int lane = threadIdx.x & 63, wv = threadIdx.x >> 6;
  if (lane == 0) wsum[wv] = s;
  __syncthreads();
  if (threadIdx.x == 0) bsum[blockIdx.x] = wsum[0] + wsum[1] + wsum[2] + wsum[3];
}

// pass2: one wave exclusive-scans B (<=64) block sums in place; writes grand total to row_ptr[N].
__global__ void scan_pass2(int* __restrict__ bsum, int* __restrict__ row_ptr, int B, int N) {
  int i = threadIdx.x;
  int v = (i < B) ? bsum[i] : 0;
  int x = v;
#pragma unroll
  for (int d = 1; d < 64; d <<= 1) {
    int y = __shfl_up(x, d, 64);
    if (i >= d) x += y;
  }
  if (i < B) bsum[i] = x - v;       // exclusive
  if (i == B - 1) row_ptr[N] = x;   // total (= E)
}

// pass3: per-block local scan + global offset -> row_ptr, cursor.
__global__ void scan_pass3(const int* __restrict__ counts, const int* __restrict__ bsum,
                           int* __restrict__ row_ptr, int* __restrict__ cursor, int N) {
  int tid = threadIdx.x, lane = tid & 63, wv = tid >> 6;
  int base = blockIdx.x * SCAN_BLK + tid * 8;
  int v[8];
  int s = 0;
  if (base < N) {
#pragma unroll
    for (int j = 0; j < 8; ++j) { v[j] = counts[base + j]; s += v[j]; }
  } else {
#pragma unroll
    for (int j = 0; j < 8; ++j) v[j] = 0;
  }
  int x = s;
#pragma unroll
  for (int d = 1; d < 64; d <<= 1) {
    int y = __shfl_up(x, d, 64);
    if (lane >= d) x += y;
  }
  __shared__ int wsum[4];
  if (lane == 63) wsum[wv] = x;
  __syncthreads();
  int woff = 0;
  for (int w = 0; w < wv; ++w) woff += wsum[w];
  int run = bsum[blockIdx.x] + woff + (x - s);   // exclusive offset of this thread's first elem
  if (base < N) {
#pragma unroll
    for (int j = 0; j < 8; ++j) {
      row_ptr[base + j] = run;
      cursor[base + j] = run;
      run += v[j];
    }
  }
}

__global__ void scatter_kernel(const int* __restrict__ rows, const int* __restrict__ cols,
                               const float* __restrict__ vals, int* __restrict__ cursor,
                               int* __restrict__ col_idx, float* __restrict__ val_srt, int E) {
  int e = blockIdx.x * 256 + threadIdx.x;
  if (e >= E) return;
  int r = rows[e];
  int p = atomicAdd(&cursor[r], 1);
  col_idx[p] = cols[e];
  val_srt[p] = vals[e];
}

// ---------------- casts / packing ----------------

__global__ void cast_bf16x4_kernel(const float* __restrict__ x, unsigned short* __restrict__ xb, int n4) {
  int i = blockIdx.x * 256 + threadIdx.x;
  if (i >= n4) return;
  floatx4 v = ((const floatx4*)x)[i];
  ushortx4 o;
  o[0] = f2bf(v[0]); o[1] = f2bf(v[1]); o[2] = f2bf(v[2]); o[3] = f2bf(v[3]);
  ((ushortx4*)xb)[i] = o;
}

// W is [K,M] row-major (in_dim, out_dim); Wp[m*K + k] = bf16(W[k,m])  (B^T layout, k contiguous)
__global__ void pack_w_kernel(const float* __restrict__ W, unsigned short* __restrict__ Wp, int K, int M) {
  int idx = blockIdx.x * 256 + threadIdx.x;
  if (idx >= K * M) return;
  int m = idx / K, k = idx - m * K;
  Wp[idx] = f2bf(W[(size_t)k * M + m]);
}

// ---------------- fused dual GEMM: S = A@W, G = A@G, written interleaved bf16 ----------------
// Block = 64 rows x M cols; wave wid owns col-tiles [wid*WT, (wid+1)*WT) across ALL 64 rows
// (4 A row-groups). B traffic per block = full W+G once per wave-column-strip -> 16x less
// L2 B-traffic than 16-rows-per-wave.  A frag: lane holds A[m=lane&15][k=quad*8+j];
// C/D: lane holds D[row=quad*4+reg][col=lane&15]  (verified, learn_hip m89/m91)
template <int MT_TOTAL>   // M = MT_TOTAL*16; WT = MT_TOTAL/4 col tiles per wave
__global__ __launch_bounds__(256) void gemm_dual_kernel(const unsigned short* __restrict__ A,
                                                        const unsigned short* __restrict__ Wp,
                                                        const unsigned short* __restrict__ Gp,
                                                        unsigned* __restrict__ SG, int N) {
  constexpr int K = 256;
  constexpr int M = MT_TOTAL * 16;
  constexpr int WT = MT_TOTAL / 4;
  int lane = threadIdx.x & 63;
  int wid = threadIdx.x >> 6;
  int r0 = blockIdx.x * 64;
  if (r0 >= N) return;
  int quad = lane >> 4, lr = lane & 15;
  int t0 = wid * WT;

  const short* Ab[4];
#pragma unroll
  for (int g = 0; g < 4; ++g) {
    int row = r0 + g * 16 + lr;
    if (row > N - 1) row = N - 1;   // clamp loads; stores guarded below
    Ab[g] = (const short*)A + (size_t)row * K + quad * 8;
  }
  const short* Wb[WT];
  const short* Gb[WT];
#pragma unroll
  for (int t = 0; t < WT; ++t) {
    size_t boff = (size_t)(t0 + t) * 16 * K + (size_t)lr * K + quad * 8;
    Wb[t] = (const short*)Wp + boff;
    Gb[t] = (const short*)Gp + boff;
  }

  floatx4 zero = {0.f, 0.f, 0.f, 0.f};
  floatx4 accS[4][WT], accG[4][WT];
#pragma unroll
  for (int g = 0; g < 4; ++g)
#pragma unroll
    for (int t = 0; t < WT; ++t) { accS[g][t] = zero; accG[g][t] = zero; }

  for (int kc = 0; kc < K / 32; ++kc) {
    short8 a[4];
#pragma unroll
    for (int g = 0; g < 4; ++g) a[g] = *(const short8*)(Ab[g] + kc * 32);
#pragma unroll
    for (int t = 0; t < WT; ++t) {
      short8 bw = *(const short8*)(Wb[t] + kc * 32);
      short8 bg = *(const short8*)(Gb[t] + kc * 32);
#pragma unroll
      for (int g = 0; g < 4; ++g) {
        accS[g][t] = __builtin_amdgcn_mfma_f32_16x16x32_bf16(a[g], bw, accS[g][t], 0, 0, 0);
        accG[g][t] = __builtin_amdgcn_mfma_f32_16x16x32_bf16(a[g], bg, accG[g][t], 0, 0, 0);
      }
    }
  }

#pragma unroll
  for (int g = 0; g < 4; ++g) {
    int orow = r0 + g * 16 + quad * 4;
#pragma unroll
    for (int t = 0; t < WT; ++t)
#pragma unroll
      for (int gg = 0; gg < 4; ++gg) {
        int row = orow + gg;
        if (row < N) {
          unsigned s = f2bf(accS[g][t][gg]);
          unsigned g2 = f2bf(accG[g][t][gg]);
          SG[(size_t)row * M + (t0 + t) * 16 + lr] = s | (g2 << 16);
        }
      }
  }
}

// ---------------- fused SpMM pair + gating (bf16 interleaved SG input) ----------------
// One wave per output row r. Per edge: single 16B (D=256) / 8B (D=128) gather per lane,
// covering interleaved {S,G} pairs. Unroll x4 for memory-level parallelism.
template <int D, bool WRITE_H>
__global__ __launch_bounds__(256) void spmm_gated_kernel(const int* __restrict__ row_ptr,
                                                         const int* __restrict__ col_idx,
                                                         const float* __restrict__ val,
                                                         const unsigned short* __restrict__ SG,
                                                         unsigned short* __restrict__ hb,
                                                         float* __restrict__ out, int N) {
  int lane = threadIdx.x & 63;
  int wid = threadIdx.x >> 6;
  int r = blockIdx.x * 4 + wid;
  if (r >= N) return;
  int e0 = row_ptr[r], e1 = row_ptr[r + 1];

  if constexpr (D == 256) {
    float aS[4] = {0.f, 0.f, 0.f, 0.f}, aG[4] = {0.f, 0.f, 0.f, 0.f};
    int e = e0;
    for (; e + 4 <= e1; e += 4) {
      int c0 = col_idx[e], c1 = col_idx[e + 1], c2 = col_idx[e + 2], c3 = col_idx[e + 3];
      float v0 = val[e], v1 = val[e + 1], v2 = val[e + 2], v3 = val[e + 3];
      short8 p0 = ((const short8*)(SG + (size_t)c0 * 512))[lane];
      short8 p1 = ((const short8*)(SG + (size_t)c1 * 512))[lane];
      short8 p2 = ((const short8*)(SG + (size_t)c2 * 512))[lane];
      short8 p3 = ((const short8*)(SG + (size_t)c3 * 512))[lane];
#pragma unroll
      for (int i = 0; i < 4; ++i) { aS[i] += bf2f(p0[2*i]) * v0; aG[i] += bf2f(p0[2*i+1]) * v0; }
#pragma unroll
      for (int i = 0; i < 4; ++i) { aS[i] += bf2f(p1[2*i]) * v1; aG[i] += bf2f(p1[2*i+1]) * v1; }
#pragma unroll
      for (int i = 0; i < 4; ++i) { aS[i] += bf2f(p2[2*i]) * v2; aG[i] += bf2f(p2[2*i+1]) * v2; }
#pragma unroll
      for (int i = 0; i < 4; ++i) { aS[i] += bf2f(p3[2*i]) * v3; aG[i] += bf2f(p3[2*i+1]) * v3; }
    }
    for (; e < e1; ++e) {
      int c = col_idx[e];
      float v = val[e];
      short8 p = ((const short8*)(SG + (size_t)c * 512))[lane];
#pragma unroll
      for (int i = 0; i < 4; ++i) { aS[i] += bf2f(p[2*i]) * v; aG[i] += bf2f(p[2*i+1]) * v; }
    }
    if constexpr (WRITE_H) {
      ushortx4 o;
#pragma unroll
      for (int i = 0; i < 4; ++i) {
        float h = sigmoidf(aG[i]) * aS[i];
        o[i] = f2bf(h > 0.f ? h : 0.f);
      }
      ((ushortx4*)(hb + (size_t)r * 256))[lane] = o;
    } else {
      floatx4 o;
#pragma unroll
      for (int i = 0; i < 4; ++i) o[i] = sigmoidf(aG[i]) * aS[i];
      ((floatx4*)(out + (size_t)r * 256))[lane] = o;
    }
  } else {  // D == 128
    float aS[2] = {0.f, 0.f}, aG[2] = {0.f, 0.f};
    int e = e0;
    for (; e + 4 <= e1; e += 4) {
      int c0 = col_idx[e], c1 = col_idx[e + 1], c2 = col_idx[e + 2], c3 = col_idx[e + 3];
      float v0 = val[e], v1 = val[e + 1], v2 = val[e + 2], v3 = val[e + 3];
      shortx4 p0 = ((const shortx4*)(SG + (size_t)c0 * 256))[lane];
      shortx4 p1 = ((const shortx4*)(SG + (size_t)c1 * 256))[lane];
      shortx4 p2 = ((const shortx4*)(SG + (size_t)c2 * 256))[lane];
      shortx4 p3 = ((const shortx4*)(SG + (size_t)c3 * 256))[lane];
#pragma unroll
      for (int i = 0; i < 2; ++i) { aS[i] += bf2f(p0[2*i]) * v0; aG[i] += bf2f(p0[2*i+1]) * v0; }
#pragma unroll
      for (int i = 0; i < 2; ++i) { aS[i] += bf2f(p1[2*i]) * v1; aG[i] += bf2f(p1[2*i+1]) * v1; }
#pragma unroll
      for (int i = 0; i < 2; ++i) { aS[i] += bf2f(p2[2*i]) * v2; aG[i] += bf2f(p2[2*i+1]) * v2; }
#pragma unroll
      for (int i = 0; i < 2; ++i) { aS[i] += bf2f(p3[2*i]) * v3; aG[i] += bf2f(p3[2*i+1]) * v3; }
    }
    for (; e < e1; ++e) {
      int c = col_idx[e];
      float v = val[e];
      shortx4 p = ((const shortx4*)(SG + (size_t)c * 256))[lane];
#pragma unroll
      for (int i = 0; i < 2; ++i) { aS[i] += bf2f(p[2*i]) * v; aG[i] += bf2f(p[2*i+1]) * v; }
    }
    floatx2 o;
#pragma unroll
    for (int i = 0; i < 2; ++i) o[i] = sigmoidf(aG[i]) * aS[i];
    ((floatx2*)(out + (size_t)r * 128))[lane] = o;
  }
}

// ---------------- launch ----------------

extern "C" void kernel_launch(void* const* d_in, const int* in_sizes, int n_in,
                              void* d_out, int out_size, void* d_ws, size_t ws_size,
                              hipStream_t stream) {
  const float* x    = (const float*)d_in[0];
  const int*   rows = (const int*)d_in[1];
  const int*   cols = (const int*)d_in[2];
  const float* vals = (const float*)d_in[3];
  const float* W1   = (const float*)d_in[4];
  const float* G1   = (const float*)d_in[5];
  const float* W2   = (const float*)d_in[6];
  const float* G2   = (const float*)d_in[7];

  const int N = N_NODES, E = N_EDGES;
  char* ws = (char*)d_ws;
  size_t off = 0;
  auto alloc = [&](size_t bytes) -> char* {
    off = (off + 255) & ~(size_t)255;
    char* p = ws + off;
    off += bytes;
    return p;
  };
  int*   counts  = (int*)alloc((size_t)N * 4);
  int*   row_ptr = (int*)alloc((size_t)(N + 1) * 4);
  int*   cursor  = (int*)alloc((size_t)N * 4);
  int*   bsum    = (int*)alloc(64 * 4);
  int*   col_idx = (int*)alloc((size_t)E * 4);
  float* val_srt = (float*)alloc((size_t)E * 4);
  unsigned short* xb  = (unsigned short*)alloc((size_t)N * 256 * 2);
  unsigned short* hb  = (unsigned short*)alloc((size_t)N * 256 * 2);
  unsigned short* Wp1 = (unsigned short*)alloc(256 * 256 * 2);
  unsigned short* Gp1 = (unsigned short*)alloc(256 * 256 * 2);
  unsigned short* Wp2 = (unsigned short*)alloc(256 * 128 * 2);
  unsigned short* Gp2 = (unsigned short*)alloc(256 * 128 * 2);
  unsigned* SG1 = (unsigned*)alloc((size_t)N * 256 * 4);   // [N][256] uints = {S,G} bf16 pairs
  unsigned* SG2 = (unsigned*)alloc((size_t)N * 128 * 4);   // [N][128] uints

  // CSR build (per launch; same work every call)
  (void)hipMemsetAsync(counts, 0, (size_t)N * 4, stream);
  count_kernel<<<(E + 255) / 256, 256, 0, stream>>>(rows, counts, E);
  int scanB = (N + SCAN_BLK - 1) / SCAN_BLK;   // 25
  scan_pass1<<<scanB, 256, 0, stream>>>(counts, bsum, N);
  scan_pass2<<<1, 64, 0, stream>>>(bsum, row_ptr, scanB, N);
  scan_pass3<<<scanB, 256, 0, stream>>>(counts, bsum, row_ptr, cursor, N);
  scatter_kernel<<<(E + 255) / 256, 256, 0, stream>>>(rows, cols, vals, cursor, col_idx, val_srt, E);

  // casts
  int n4 = N * 256 / 4;
  cast_bf16x4_kernel<<<(n4 + 255) / 256, 256, 0, stream>>>(x, xb, n4);
  pack_w_kernel<<<(256 * 256 + 255) / 256, 256, 0, stream>>>(W1, Wp1, 256, 256);
  pack_w_kernel<<<(256 * 256 + 255) / 256, 256, 0, stream>>>(G1, Gp1, 256, 256);
  pack_w_kernel<<<(256 * 128 + 255) / 256, 256, 0, stream>>>(W2, Wp2, 256, 128);
  pack_w_kernel<<<(256 * 128 + 255) / 256, 256, 0, stream>>>(G2, Gp2, 256, 128);

  int gemm_blocks = (N + 63) / 64;
  int spmm_blocks = (N + 3) / 4;

  // layer 1
  gemm_dual_kernel<16><<<gemm_blocks, 256, 0, stream>>>(xb, Wp1, Gp1, SG1, N);
  spmm_gated_kernel<256, true><<<spmm_blocks, 256, 0, stream>>>(row_ptr, col_idx, val_srt,
                                                                (const unsigned short*)SG1, hb, nullptr, N);
  // layer 2
  gemm_dual_kernel<8><<<gemm_blocks, 256, 0, stream>>>(hb, Wp2, Gp2, SG2, N);
  spmm_gated_kernel<128, false><<<spmm_blocks, 256, 0, stream>>>(row_ptr, col_idx, val_srt,
                                                                 (const unsigned short*)SG2, nullptr, (float*)d_out, N);
}

// Round 5
// 458.605 us; speedup vs baseline: 1.9283x; 1.0108x over previous
//
#include <hip/hip_runtime.h>
#include <math.h>

#define N_NODES 50000
#define N_EDGES 800000
#define SCAN_BLK 2048   // elements per scan block (256 threads x 8)

using short8  = __attribute__((ext_vector_type(8))) short;
using floatx4 = __attribute__((ext_vector_type(4))) float;
using floatx2 = __attribute__((ext_vector_type(2))) float;
using ushortx4 = __attribute__((ext_vector_type(4))) unsigned short;
using uintx4  = __attribute__((ext_vector_type(4))) unsigned;
using uintx2  = __attribute__((ext_vector_type(2))) unsigned;

__device__ inline unsigned short f2bf(float f) {
  unsigned u = __float_as_uint(f);
  u += 0x7fff + ((u >> 16) & 1);   // round-to-nearest-even
  return (unsigned short)(u >> 16);
}

__device__ inline float sigmoidf(float x) { return 1.0f / (1.0f + __expf(-x)); }

// ---------------- CSR build ----------------

__global__ void count_kernel(const int* __restrict__ rows, int* __restrict__ counts, int E) {
  int e = blockIdx.x * 256 + threadIdx.x;
  if (e < E) atomicAdd(&counts[rows[e]], 1);
}

// pass1: per-block sums. N % 8 == 0 so (base < N) => full 8 in-bounds.
__global__ void scan_pass1(const int* __restrict__ counts, int* __restrict__ bsum, int N) {
  int base = blockIdx.x * SCAN_BLK + threadIdx.x * 8;
  int s = 0;
  if (base < N) {
#pragma unroll
    for (int j = 0; j < 8; ++j) s += counts[base + j];
  }
#pragma unroll
  for (int d = 32; d > 0; d >>= 1) s += __shfl_down(s, d, 64);
  __shared__ int wsum[4];
  int lane = threadIdx.x & 63, wv = threadIdx.x >> 6;
  if (lane == 0) wsum[wv] = s;
  __syncthreads();
  if (threadIdx.x == 0) bsum[blockIdx.x] = wsum[0] + wsum[1] + wsum[2] + wsum[3];
}

// pass2: one wave exclusive-scans B (<=64) block sums in place; writes grand total to row_ptr[N].
__global__ void scan_pass2(int* __restrict__ bsum, int* __restrict__ row_ptr, int B, int N) {
  int i = threadIdx.x;
  int v = (i < B) ? bsum[i] : 0;
  int x = v;
#pragma unroll
  for (int d = 1; d < 64; d <<= 1) {
    int y = __shfl_up(x, d, 64);
    if (i >= d) x += y;
  }
  if (i < B) bsum[i] = x - v;       // exclusive
  if (i == B - 1) row_ptr[N] = x;   // total (= E)
}

// pass3: per-block local scan + global offset -> row_ptr, cursor.
__global__ void scan_pass3(const int* __restrict__ counts, const int* __restrict__ bsum,
                           int* __restrict__ row_ptr, int* __restrict__ cursor, int N) {
  int tid = threadIdx.x, lane = tid & 63, wv = tid >> 6;
  int base = blockIdx.x * SCAN_BLK + tid * 8;
  int v[8];
  int s = 0;
  if (base < N) {
#pragma unroll
    for (int j = 0; j < 8; ++j) { v[j] = counts[base + j]; s += v[j]; }
  } else {
#pragma unroll
    for (int j = 0; j < 8; ++j) v[j] = 0;
  }
  int x = s;
#pragma unroll
  for (int d = 1; d < 64; d <<= 1) {
    int y = __shfl_up(x, d, 64);
    if (lane >= d) x += y;
  }
  __shared__ int wsum[4];
  if (lane == 63) wsum[wv] = x;
  __syncthreads();
  int woff = 0;
  for (int w = 0; w < wv; ++w) woff += wsum[w];
  int run = bsum[blockIdx.x] + woff + (x - s);   // exclusive offset of this thread's first elem
  if (base < N) {
#pragma unroll
    for (int j = 0; j < 8; ++j) {
      row_ptr[base + j] = run;
      cursor[base + j] = run;
      run += v[j];
    }
  }
}

__global__ void scatter_kernel(const int* __restrict__ rows, const int* __restrict__ cols,
                               const float* __restrict__ vals, int* __restrict__ cursor,
                               int* __restrict__ col_idx, float* __restrict__ val_srt, int E) {
  int e = blockIdx.x * 256 + threadIdx.x;
  if (e >= E) return;
  int r = rows[e];
  int p = atomicAdd(&cursor[r], 1);
  col_idx[p] = cols[e];
  val_srt[p] = vals[e];
}

// ---------------- casts / packing ----------------

__global__ void cast_bf16x4_kernel(const float* __restrict__ x, unsigned short* __restrict__ xb, int n4) {
  int i = blockIdx.x * 256 + threadIdx.x;
  if (i >= n4) return;
  floatx4 v = ((const floatx4*)x)[i];
  ushortx4 o;
  o[0] = f2bf(v[0]); o[1] = f2bf(v[1]); o[2] = f2bf(v[2]); o[3] = f2bf(v[3]);
  ((ushortx4*)xb)[i] = o;
}

// All 4 weights packed in one launch. W [K,M] row-major -> Wp[m*K+k] = bf16(W[k,m]).
// W1/G1: K=256,M=256 (65536 each); W2/G2: K=256,M=128 (32768 each). Total 196608.
__global__ void pack_all_kernel(const float* __restrict__ W1, const float* __restrict__ G1,
                                const float* __restrict__ W2, const float* __restrict__ G2,
                                unsigned short* __restrict__ Wp1, unsigned short* __restrict__ Gp1,
                                unsigned short* __restrict__ Wp2, unsigned short* __restrict__ Gp2) {
  int idx = blockIdx.x * 256 + threadIdx.x;
  if (idx < 65536) {
    int m = idx >> 8, k = idx & 255;
    Wp1[idx] = f2bf(W1[k * 256 + m]);
  } else if (idx < 131072) {
    int t = idx - 65536; int m = t >> 8, k = t & 255;
    Gp1[t] = f2bf(G1[k * 256 + m]);
  } else if (idx < 163840) {
    int t = idx - 131072; int m = t >> 8, k = t & 255;
    Wp2[t] = f2bf(W2[k * 128 + m]);
  } else {
    int t = idx - 163840; int m = t >> 8, k = t & 255;
    Gp2[t] = f2bf(G2[k * 128 + m]);
  }
}

// ---------------- fused dual GEMM: S = A@W, G = A@G, written interleaved bf16 ----------------
// Block = 64 rows x M cols; wave wid owns col-tiles [wid*WT, (wid+1)*WT) across ALL 64 rows.
// A frag: lane holds A[m=lane&15][k=quad*8+j]; C/D: D[row=quad*4+reg][col=lane&15] (m89/m91)
template <int MT_TOTAL>   // M = MT_TOTAL*16; WT = MT_TOTAL/4 col tiles per wave
__global__ __launch_bounds__(256) void gemm_dual_kernel(const unsigned short* __restrict__ A,
                                                        const unsigned short* __restrict__ Wp,
                                                        const unsigned short* __restrict__ Gp,
                                                        unsigned* __restrict__ SG, int N) {
  constexpr int K = 256;
  constexpr int M = MT_TOTAL * 16;
  constexpr int WT = MT_TOTAL / 4;
  int lane = threadIdx.x & 63;
  int wid = threadIdx.x >> 6;
  int r0 = blockIdx.x * 64;
  if (r0 >= N) return;
  int quad = lane >> 4, lr = lane & 15;
  int t0 = wid * WT;

  const short* Ab[4];
#pragma unroll
  for (int g = 0; g < 4; ++g) {
    int row = r0 + g * 16 + lr;
    if (row > N - 1) row = N - 1;   // clamp loads; stores guarded below
    Ab[g] = (const short*)A + (size_t)row * K + quad * 8;
  }
  const short* Wb[WT];
  const short* Gb[WT];
#pragma unroll
  for (int t = 0; t < WT; ++t) {
    size_t boff = (size_t)(t0 + t) * 16 * K + (size_t)lr * K + quad * 8;
    Wb[t] = (const short*)Wp + boff;
    Gb[t] = (const short*)Gp + boff;
  }

  floatx4 zero = {0.f, 0.f, 0.f, 0.f};
  floatx4 accS[4][WT], accG[4][WT];
#pragma unroll
  for (int g = 0; g < 4; ++g)
#pragma unroll
    for (int t = 0; t < WT; ++t) { accS[g][t] = zero; accG[g][t] = zero; }

  for (int kc = 0; kc < K / 32; ++kc) {
    short8 a[4];
#pragma unroll
    for (int g = 0; g < 4; ++g) a[g] = *(const short8*)(Ab[g] + kc * 32);
#pragma unroll
    for (int t = 0; t < WT; ++t) {
      short8 bw = *(const short8*)(Wb[t] + kc * 32);
      short8 bg = *(const short8*)(Gb[t] + kc * 32);
#pragma unroll
      for (int g = 0; g < 4; ++g) {
        accS[g][t] = __builtin_amdgcn_mfma_f32_16x16x32_bf16(a[g], bw, accS[g][t], 0, 0, 0);
        accG[g][t] = __builtin_amdgcn_mfma_f32_16x16x32_bf16(a[g], bg, accG[g][t], 0, 0, 0);
      }
    }
  }

#pragma unroll
  for (int g = 0; g < 4; ++g) {
    int orow = r0 + g * 16 + quad * 4;
#pragma unroll
    for (int t = 0; t < WT; ++t)
#pragma unroll
      for (int gg = 0; gg < 4; ++gg) {
        int row = orow + gg;
        if (row < N) {
          unsigned s = f2bf(accS[g][t][gg]);
          unsigned g2 = f2bf(accG[g][t][gg]);
          SG[(size_t)row * M + (t0 + t) * 16 + lr] = s | (g2 << 16);
        }
      }
  }
}

// ---------------- fused SpMM pair + gating (bf16 interleaved SG input) ----------------
// One wave per output row r. Metadata for 64 edges loaded once (lane-parallel) and
// broadcast via __shfl; gathers issued 8 at a time for MLP. Pad lanes carry v=0 so
// remainder batches stay fully pipelined. Gate read as asfloat(u) directly: low-16
// S bits perturb G mantissa by <2^-8 rel (one extra bf16-grade rounding), saves VALU.
template <int D, bool WRITE_H>
__global__ __launch_bounds__(256) void spmm_gated_kernel(const int* __restrict__ row_ptr,
                                                         const int* __restrict__ col_idx,
                                                         const float* __restrict__ val,
                                                         const unsigned* __restrict__ SG,
                                                         unsigned short* __restrict__ hb,
                                                         float* __restrict__ out, int N) {
  constexpr int PF = D / 64;   // uints (SG pairs) per lane: 4 for D=256, 2 for D=128
  using uvec = typename std::conditional<PF == 4, uintx4, uintx2>::type;
  int lane = threadIdx.x & 63;
  int wid = threadIdx.x >> 6;
  int r = blockIdx.x * 4 + wid;
  if (r >= N) return;
  int e0 = row_ptr[r], e1 = row_ptr[r + 1];

  float aS[PF], aG[PF];
#pragma unroll
  for (int i = 0; i < PF; ++i) { aS[i] = 0.f; aG[i] = 0.f; }

  for (int base = e0; base < e1; base += 64) {
    int cnt = e1 - base;
    if (cnt > 64) cnt = 64;
    int idx = base + ((lane < cnt) ? lane : 0);
    int ce = col_idx[idx];
    float ve = (lane < cnt) ? val[idx] : 0.f;
    for (int j = 0; j < cnt; j += 8) {
      unsigned c[8];
      float v[8];
#pragma unroll
      for (int i = 0; i < 8; ++i) {
        c[i] = (unsigned)__shfl(ce, j + i, 64);
        v[i] = __shfl(ve, j + i, 64);
      }
      uvec p[8];
#pragma unroll
      for (int i = 0; i < 8; ++i)
        p[i] = ((const uvec*)(SG + (size_t)c[i] * D))[lane];
#pragma unroll
      for (int i = 0; i < 8; ++i)
#pragma unroll
        for (int q = 0; q < PF; ++q) {
          unsigned u = p[i][q];
          aS[q] += __uint_as_float(u << 16) * v[i];
          aG[q] += __uint_as_float(u) * v[i];   // G + <2^-8 rel mantissa noise
        }
    }
  }

  if constexpr (WRITE_H) {
    ushortx4 o;
#pragma unroll
    for (int i = 0; i < PF; ++i) {
      float h = sigmoidf(aG[i]) * aS[i];
      o[i] = f2bf(h > 0.f ? h : 0.f);
    }
    ((ushortx4*)(hb + (size_t)r * 256))[lane] = o;   // only instantiated with D=256
  } else {
    if constexpr (PF == 4) {
      floatx4 o;
#pragma unroll
      for (int i = 0; i < 4; ++i) o[i] = sigmoidf(aG[i]) * aS[i];
      ((floatx4*)(out + (size_t)r * D))[lane] = o;
    } else {
      floatx2 o;
#pragma unroll
      for (int i = 0; i < 2; ++i) o[i] = sigmoidf(aG[i]) * aS[i];
      ((floatx2*)(out + (size_t)r * D))[lane] = o;
    }
  }
}

// ---------------- launch ----------------

extern "C" void kernel_launch(void* const* d_in, const int* in_sizes, int n_in,
                              void* d_out, int out_size, void* d_ws, size_t ws_size,
                              hipStream_t stream) {
  const float* x    = (const float*)d_in[0];
  const int*   rows = (const int*)d_in[1];
  const int*   cols = (const int*)d_in[2];
  const float* vals = (const float*)d_in[3];
  const float* W1   = (const float*)d_in[4];
  const float* G1   = (const float*)d_in[5];
  const float* W2   = (const float*)d_in[6];
  const float* G2   = (const float*)d_in[7];

  const int N = N_NODES, E = N_EDGES;
  char* ws = (char*)d_ws;
  size_t off = 0;
  auto alloc = [&](size_t bytes) -> char* {
    off = (off + 255) & ~(size_t)255;
    char* p = ws + off;
    off += bytes;
    return p;
  };
  int*   counts  = (int*)alloc((size_t)N * 4);
  int*   row_ptr = (int*)alloc((size_t)(N + 1) * 4);
  int*   cursor  = (int*)alloc((size_t)N * 4);
  int*   bsum    = (int*)alloc(64 * 4);
  int*   col_idx = (int*)alloc((size_t)E * 4);
  float* val_srt = (float*)alloc((size_t)E * 4);
  unsigned short* xb  = (unsigned short*)alloc((size_t)N * 256 * 2);
  unsigned short* hb  = (unsigned short*)alloc((size_t)N * 256 * 2);
  unsigned short* Wp1 = (unsigned short*)alloc(256 * 256 * 2);
  unsigned short* Gp1 = (unsigned short*)alloc(256 * 256 * 2);
  unsigned short* Wp2 = (unsigned short*)alloc(256 * 128 * 2);
  unsigned short* Gp2 = (unsigned short*)alloc(256 * 128 * 2);
  unsigned* SG1 = (unsigned*)alloc((size_t)N * 256 * 4);   // [N][256] uints = {S,G} bf16 pairs
  unsigned* SG2 = (unsigned*)alloc((size_t)N * 128 * 4);   // [N][128] uints

  // CSR build (per launch; same work every call)
  (void)hipMemsetAsync(counts, 0, (size_t)N * 4, stream);
  count_kernel<<<(E + 255) / 256, 256, 0, stream>>>(rows, counts, E);
  int scanB = (N + SCAN_BLK - 1) / SCAN_BLK;   // 25
  scan_pass1<<<scanB, 256, 0, stream>>>(counts, bsum, N);
  scan_pass2<<<1, 64, 0, stream>>>(bsum, row_ptr, scanB, N);
  scan_pass3<<<scanB, 256, 0, stream>>>(counts, bsum, row_ptr, cursor, N);
  scatter_kernel<<<(E + 255) / 256, 256, 0, stream>>>(rows, cols, vals, cursor, col_idx, val_srt, E);

  // casts (fused weight pack: 196608 elems -> 768 blocks)
  int n4 = N * 256 / 4;
  cast_bf16x4_kernel<<<(n4 + 255) / 256, 256, 0, stream>>>(x, xb, n4);
  pack_all_kernel<<<768, 256, 0, stream>>>(W1, G1, W2, G2, Wp1, Gp1, Wp2, Gp2);

  int gemm_blocks = (N + 63) / 64;
  int spmm_blocks = (N + 3) / 4;

  // layer 1
  gemm_dual_kernel<16><<<gemm_blocks, 256, 0, stream>>>(xb, Wp1, Gp1, SG1, N);
  spmm_gated_kernel<256, true><<<spmm_blocks, 256, 0, stream>>>(row_ptr, col_idx, val_srt,
                                                                SG1, hb, nullptr, N);
  // layer 2
  gemm_dual_kernel<8><<<gemm_blocks, 256, 0, stream>>>(hb, Wp2, Gp2, SG2, N);
  spmm_gated_kernel<128, false><<<spmm_blocks, 256, 0, stream>>>(row_ptr, col_idx, val_srt,
                                                                 SG2, nullptr, (float*)d_out, N);
}